// Round 4
// baseline (408.207 us; speedup 1.0000x reference)
//
#include <hip/hip_runtime.h>
#include <math.h>

#define D 64
#define CHUNK 8192
#define MS_T 1024
#define EPT 8           // CHUNK / MS_T
#define MAXNB 800       // >= nbk = ceil(n/128); n=100000 -> 782
#define NPW 4           // nodes per wave per quarter-pass in gather kernels

typedef __attribute__((ext_vector_type(8))) short frag_ab;
typedef __attribute__((ext_vector_type(4))) float frag_cd;
typedef __attribute__((ext_vector_type(2))) float v2f;
typedef __attribute__((ext_vector_type(4))) float v4f;
typedef __attribute__((ext_vector_type(2))) unsigned v2u;

__device__ __forceinline__ unsigned short f2bf(float f) {
    unsigned u = __float_as_uint(f);
    u += 0x7FFFu + ((u >> 16) & 1u);
    return (unsigned short)(u >> 16);
}
__device__ __forceinline__ float bf2f(unsigned short s) {
    return __uint_as_float(((unsigned)s) << 16);
}
// tanh for x >= 0, branch-free, ~5 VALU. |err| ~1e-6 vs absmax budget 2e-2.
__device__ __forceinline__ float fast_tanh_pos(float x) {
    float t = __expf(-2.0f * x);
    return (1.0f - t) * __builtin_amdgcn_rcpf(1.0f + t);
}

// ---------------------------------------------------------------------------
// bucket_hist: per-chunk LDS histogram over 128-node buckets (verified).
// Last block instead packs W into MFMA fragment layout (R4-verified) and
// zeroes ylq row n (the masked-lane zero row).
// ---------------------------------------------------------------------------
__global__ __launch_bounds__(MS_T) void bucket_hist(
    const int* __restrict__ ei, int n_edges, int nbk,
    int* __restrict__ bc_col, int* __restrict__ bc_row,
    const float* __restrict__ Wl, const float* __restrict__ Wr,
    unsigned short* __restrict__ wpack, unsigned* __restrict__ ylq, int n)
{
    __shared__ int scol[MAXNB];
    __shared__ int srow[MAXNB];

    if (blockIdx.x == gridDim.x - 1) {          // pack_w + zero row
        if (threadIdx.x < 256) {
            for (int c = threadIdx.x; c < 8192; c += 256) {
                int j = c & 7;
                int lane = (c >> 3) & 63;
                int tile = (c >> 9) & 7;
                int mat = c >> 12;
                int kc = tile >> 2;
                int nt = tile & 3;
                int krow = (lane >> 4) * 8 + j + kc * 32;
                int col = (lane & 15) + nt * 16;
                const float* W = mat ? Wr : Wl;
                float v = W[krow * 64 + col];
                unsigned short hi = f2bf(v);
                unsigned short lo = f2bf(v - bf2f(hi));
                int base = mat * 8192 + tile * 512 + lane * 8 + j;
                wpack[base] = hi;
                wpack[base + 4096] = lo;
            }
            if (threadIdx.x < 32) {             // ylq row n = zeros, all quarters
                int q = threadIdx.x >> 3, k = threadIdx.x & 7;
                ylq[((size_t)q * (n + 1) + n) * 8 + k] = 0u;
            }
        }
        return;
    }

    for (int t = threadIdx.x; t < nbk; t += MS_T) {
        scol[t] = 0;
        srow[t] = 0;
    }
    __syncthreads();

    int base = blockIdx.x * CHUNK;
    int cc = n_edges - base;
    if (cc > CHUNK) cc = CHUNK;
    #pragma unroll
    for (int k = 0; k < EPT; ++k) {
        int i = threadIdx.x + k * MS_T;
        if (i < cc) {
            int r = ei[base + i];
            int c = ei[n_edges + base + i];
            atomicAdd(&srow[r >> 7], 1);
            atomicAdd(&scol[c >> 7], 1);
        }
    }
    __syncthreads();
    for (int t = threadIdx.x; t < nbk; t += MS_T) {
        if (scol[t]) atomicAdd(&bc_col[t], scol[t]);
        if (srow[t]) atomicAdd(&bc_row[t], srow[t]);
    }
}

// ---------------------------------------------------------------------------
// scan 782 bucket counts -> bases; init cursors (verified)
// ---------------------------------------------------------------------------
__global__ __launch_bounds__(64) void bucket_scan(
    const int* __restrict__ bc_col, const int* __restrict__ bc_row,
    int* __restrict__ bbase_col, int* __restrict__ bbase_row,
    int* __restrict__ gcur_col, int* __restrict__ gcur_row, int nbk)
{
    int lane = threadIdx.x;
    for (int w = 0; w < 2; ++w) {
        const int* bc = w ? bc_row : bc_col;
        int* bb = w ? bbase_row : bbase_col;
        int* gc = w ? gcur_row : gcur_col;
        int carry = 0;
        for (int b0 = 0; b0 < nbk; b0 += 64) {
            int v = (b0 + lane < nbk) ? bc[b0 + lane] : 0;
            int x = v;
            #pragma unroll
            for (int o = 1; o < 64; o <<= 1) {
                int u = __shfl_up(x, o);
                if (lane >= o) x += u;
            }
            if (b0 + lane < nbk) {
                int e = carry + x - v;
                bb[b0 + lane] = e;
                gc[b0 + lane] = e;
            }
            carry += __shfl(x, 63);
        }
    }
}

// ---------------------------------------------------------------------------
// Multisplit (verified): group edges into 128-node buckets, both orders.
// ---------------------------------------------------------------------------
__global__ __launch_bounds__(MS_T) void multisplit(
    const int* __restrict__ ei, int n_edges, int nbk,
    int* __restrict__ gcur_col, int* __restrict__ gcur_row,
    unsigned* __restrict__ ecol, unsigned* __restrict__ erow)
{
    __shared__ unsigned stage[CHUNK];
    __shared__ unsigned short sbk[CHUNK];
    __shared__ int cnt[MAXNB];
    __shared__ int off[MAXNB + 1];
    __shared__ int gb[MAXNB];

    int base = blockIdx.x * CHUNK;
    int cc = n_edges - base;
    if (cc > CHUNK) cc = CHUNK;

    int r[EPT], c[EPT];
    #pragma unroll
    for (int k = 0; k < EPT; ++k) {
        int i = threadIdx.x + k * MS_T;
        if (i < cc) {
            r[k] = ei[base + i];
            c[k] = ei[n_edges + base + i];
        }
    }

    for (int ord = 0; ord < 2; ++ord) {
        int* gcur = ord ? gcur_row : gcur_col;
        unsigned* eout = ord ? erow : ecol;

        for (int t = threadIdx.x; t < nbk; t += MS_T) cnt[t] = 0;
        __syncthreads();

        int rk[EPT], bk[EPT];
        #pragma unroll
        for (int k = 0; k < EPT; ++k) {
            int i = threadIdx.x + k * MS_T;
            if (i < cc) {
                int key = ord ? r[k] : c[k];
                bk[k] = key >> 7;
                rk[k] = atomicAdd(&cnt[bk[k]], 1);
            }
        }
        __syncthreads();

        if (threadIdx.x < 64) {           // wave 0: scan + global reservation
            int lane = threadIdx.x;
            int carry = 0;
            for (int b0 = 0; b0 < nbk; b0 += 64) {
                int v = (b0 + lane < nbk) ? cnt[b0 + lane] : 0;
                int x = v;
                #pragma unroll
                for (int o = 1; o < 64; o <<= 1) {
                    int u = __shfl_up(x, o);
                    if (lane >= o) x += u;
                }
                if (b0 + lane < nbk) {
                    off[b0 + lane] = carry + x - v;
                    gb[b0 + lane] = v ? atomicAdd(&gcur[b0 + lane], v) : 0;
                }
                carry += __shfl(x, 63);
            }
        }
        __syncthreads();

        #pragma unroll
        for (int k = 0; k < EPT; ++k) {
            int i = threadIdx.x + k * MS_T;
            if (i < cc) {
                int key = ord ? r[k] : c[k];
                int oth = ord ? c[k] : r[k];
                int p = off[bk[k]] + rk[k];
                stage[p] = ((unsigned)(key & 127) << 17) | (unsigned)oth;
                sbk[p] = (unsigned short)bk[k];
            }
        }
        __syncthreads();

        for (int t = threadIdx.x; t < cc; t += MS_T) {
            int bb = sbk[t];
            eout[gb[bb] + (t - off[bb])] = stage[t];
        }
        __syncthreads();
    }
}

// ---------------------------------------------------------------------------
// csr_build (verified): bucket entries -> exact per-node CSR.
// ---------------------------------------------------------------------------
__global__ __launch_bounds__(256) void csr_build(
    const unsigned* __restrict__ ecol, const unsigned* __restrict__ erow,
    const int* __restrict__ bbase_col, const int* __restrict__ bbase_row,
    const int* __restrict__ bc_col, const int* __restrict__ bc_row,
    int* __restrict__ off_col, int* __restrict__ off_row,
    int* __restrict__ by_col, int* __restrict__ by_row, int n, int nbk)
{
    __shared__ int scnt[128];
    __shared__ int soff[129];
    bool isRow = blockIdx.x >= (unsigned)nbk;
    int b = isRow ? (blockIdx.x - nbk) : blockIdx.x;
    const unsigned* e = isRow ? erow : ecol;
    int base = (isRow ? bbase_row : bbase_col)[b];
    int ec = (isRow ? bc_row : bc_col)[b];
    int* off_g = isRow ? off_row : off_col;
    int* by = isRow ? by_row : by_col;

    int node0 = b << 7;
    int nn = n - node0;
    if (nn > 128) nn = 128;

    if (threadIdx.x < 128) scnt[threadIdx.x] = 0;
    __syncthreads();

    for (int t = threadIdx.x; t < ec; t += 256)
        atomicAdd(&scnt[e[base + t] >> 17], 1);
    __syncthreads();

    if (threadIdx.x < 64) {
        int lane = threadIdx.x;
        int carry = 0;
        #pragma unroll
        for (int b0 = 0; b0 < 128; b0 += 64) {
            int v = scnt[b0 + lane];
            int x = v;
            #pragma unroll
            for (int o = 1; o < 64; o <<= 1) {
                int u = __shfl_up(x, o);
                if (lane >= o) x += u;
            }
            soff[b0 + lane] = carry + x - v;
            carry += __shfl(x, 63);
        }
        if (lane == 63) soff[128] = carry;
    }
    __syncthreads();

    if (threadIdx.x < 128) {
        if (threadIdx.x < nn) off_g[node0 + threadIdx.x] = base + soff[threadIdx.x];
        scnt[threadIdx.x] = 0;
    }
    if (threadIdx.x == 0 && node0 + nn == n) off_g[n] = base + soff[nn];
    __syncthreads();

    for (int t = threadIdx.x; t < ec; t += 256) {
        unsigned ent = e[base + t];
        int slot = ent >> 17;
        int r = atomicAdd(&scnt[slot], 1);
        by[base + soff[slot] + r] = (int)(ent & 0x1FFFF);
    }
}

// ---------------------------------------------------------------------------
// gemm_x: Yl = X@Wl (packed bf16, quarter-major) and Yr = X@Wr + b (f32,
// quarter-major), reading X once. agg@Wl == mean(Yl[rows]) by linearity.
// MFMA math identical to the verified linear_mfma (split-bf16, 3 MFMA/term).
// ---------------------------------------------------------------------------
__global__ __launch_bounds__(256) void gemm_x(
    const float* __restrict__ X, const unsigned short* __restrict__ wpack,
    const float* __restrict__ b, unsigned* __restrict__ ylq,
    float* __restrict__ yrq, int n, int ngroups)
{
    int lane = threadIdx.x & 63;
    int g = (blockIdx.x * blockDim.x + threadIdx.x) >> 6;
    if (g >= ngroups) return;
    int quad = lane >> 4;
    int l15 = lane & 15;

    frag_ab wf[2][2][2][4];
    #pragma unroll
    for (int mat = 0; mat < 2; ++mat)
        #pragma unroll
        for (int hf = 0; hf < 2; ++hf)
            #pragma unroll
            for (int kc = 0; kc < 2; ++kc)
                #pragma unroll
                for (int nt = 0; nt < 4; ++nt) {
                    const unsigned short* p =
                        wpack + mat * 8192 + hf * 4096 + (kc * 4 + nt) * 512 + lane * 8;
                    wf[mat][hf][kc][nt] = *(const frag_ab*)p;
                }

    frag_cd accl[4], accr[4];
    #pragma unroll
    for (int nt = 0; nt < 4; ++nt) {
        accl[nt] = (frag_cd){0.f, 0.f, 0.f, 0.f};
        accr[nt] = (frag_cd){0.f, 0.f, 0.f, 0.f};
    }

    int mrow = g * 16 + l15;
    if (mrow >= n) mrow = n - 1;
    const float* xrow = X + ((size_t)mrow << 6) + quad * 8;

    #pragma unroll
    for (int kc = 0; kc < 2; ++kc) {
        float xv[8];
        #pragma unroll
        for (int t = 0; t < 2; ++t) {
            float4 x4 = *(const float4*)(xrow + kc * 32 + t * 4);
            xv[t * 4 + 0] = x4.x; xv[t * 4 + 1] = x4.y;
            xv[t * 4 + 2] = x4.z; xv[t * 4 + 3] = x4.w;
        }
        frag_ab xh, xl;
        #pragma unroll
        for (int j = 0; j < 8; ++j) {
            unsigned short xbv = f2bf(xv[j]);
            xh[j] = (short)xbv;
            xl[j] = (short)f2bf(xv[j] - bf2f(xbv));
        }
        #pragma unroll
        for (int nt = 0; nt < 4; ++nt) {
            accl[nt] = __builtin_amdgcn_mfma_f32_16x16x32_bf16(xh, wf[0][0][kc][nt], accl[nt], 0, 0, 0);
            accl[nt] = __builtin_amdgcn_mfma_f32_16x16x32_bf16(xh, wf[0][1][kc][nt], accl[nt], 0, 0, 0);
            accl[nt] = __builtin_amdgcn_mfma_f32_16x16x32_bf16(xl, wf[0][0][kc][nt], accl[nt], 0, 0, 0);
            accr[nt] = __builtin_amdgcn_mfma_f32_16x16x32_bf16(xh, wf[1][0][kc][nt], accr[nt], 0, 0, 0);
            accr[nt] = __builtin_amdgcn_mfma_f32_16x16x32_bf16(xh, wf[1][1][kc][nt], accr[nt], 0, 0, 0);
            accr[nt] = __builtin_amdgcn_mfma_f32_16x16x32_bf16(xl, wf[1][0][kc][nt], accr[nt], 0, 0, 0);
        }
    }

    size_t qs_yl = (size_t)(n + 1) << 3;      // u32 per ylq quarter
    #pragma unroll
    for (int nt = 0; nt < 4; ++nt) {
        float bj = b[l15 + nt * 16];
        #pragma unroll
        for (int r = 0; r < 4; ++r) {
            int row = quad * 4 + r;
            int node = g * 16 + row;
            float vl = accl[nt][r];
            float vr = accr[nt][r] + bj;
            float vln = __shfl_xor(vl, 1);    // neighbor feature (l15^1)
            if (node < n) {
                yrq[(size_t)nt * ((size_t)n << 4) + ((size_t)node << 4) + l15] = vr;
                if ((l15 & 1) == 0) {
                    unsigned pk = (unsigned)f2bf(vl) | ((unsigned)f2bf(vln) << 16);
                    ylq[(size_t)nt * qs_yl + ((size_t)node << 3) + (l15 >> 1)] = pk;
                }
            }
        }
    }
}

// ---------------------------------------------------------------------------
// h_gather: 4 feature-quarter passes (qtr = blockIdx major so the grid sweeps
// one 3.2MB L2-resident table quarter at a time). 4 lanes/edge x 8B = 32B.
// h = relu(mean(Yl[row]) + Yr[u]) -> packed bf16, quarter-major (hbq).
// Streaming traffic (by, yr, hbq) is non-temporal to protect L2 residency.
// ---------------------------------------------------------------------------
__global__ __launch_bounds__(256) void h_gather(
    const unsigned* __restrict__ ylq, const float* __restrict__ yrq,
    const int* __restrict__ off_col, const int* __restrict__ by_col,
    unsigned* __restrict__ hbq, int n, int nb_per_q)
{
    int qtr = blockIdx.x / nb_per_q;
    int blk = blockIdx.x - qtr * nb_per_q;
    int lane = threadIdx.x & 63;
    int wid = threadIdx.x >> 6;
    int fl = lane & 3, q16 = lane >> 2;

    const unsigned* tab = ylq + (size_t)qtr * ((size_t)(n + 1) << 3);
    const float* yq = yrq + (size_t)qtr * ((size_t)n << 4);
    unsigned* hq = hbq + (size_t)qtr * ((size_t)n << 3);

    int node0 = (blk * 4 + wid) * NPW;
    for (int nn = 0; nn < NPW; ++nn) {
        int node = node0 + nn;
        if (node >= n) break;
        int s0 = off_col[node], s1 = off_col[node + 1];
        v2f a01 = {0.f, 0.f}, a23 = {0.f, 0.f};
        for (int base = s0; base < s1; base += 64) {
            int m = s1 - base;
            if (m > 64) m = 64;
            int idx = (lane < m) ? __builtin_nontemporal_load(by_col + base + lane) : n;
            for (int j = 0; j < m; j += 16) {
                int e = __shfl(idx, j + q16);          // 16 edges in flight
                uint2 v = ((const uint2*)tab)[((size_t)e << 2) + fl];
                v2f h01, h23;
                h01.x = __uint_as_float(v.x << 16);
                h01.y = __uint_as_float(v.x & 0xFFFF0000u);
                h23.x = __uint_as_float(v.y << 16);
                h23.y = __uint_as_float(v.y & 0xFFFF0000u);
                a01 += h01;
                a23 += h23;
            }
        }
        #pragma unroll
        for (int o = 4; o < 64; o <<= 1) {             // reduce the 16 q-groups
            a01.x += __shfl_xor(a01.x, o);
            a01.y += __shfl_xor(a01.y, o);
            a23.x += __shfl_xor(a23.x, o);
            a23.y += __shfl_xor(a23.y, o);
        }
        if (lane < 4) {
            float inv = 1.f / fmaxf((float)(s1 - s0), 1.f);
            v4f yv = __builtin_nontemporal_load(
                (const v4f*)(yq + ((size_t)node << 4)) + fl);
            float h0 = fmaxf(a01.x * inv + yv.x, 0.f);
            float h1 = fmaxf(a01.y * inv + yv.y, 0.f);
            float h2 = fmaxf(a23.x * inv + yv.z, 0.f);
            float h3 = fmaxf(a23.y * inv + yv.w, 0.f);
            v2u pk;
            pk.x = (unsigned)f2bf(h0) | ((unsigned)f2bf(h1) << 16);
            pk.y = (unsigned)f2bf(h2) | ((unsigned)f2bf(h3) << 16);
            __builtin_nontemporal_store(pk, (v2u*)hq + ((size_t)node << 2) + fl);
        }
    }
}

// ---------------------------------------------------------------------------
// gate4: same 4-pass quartered structure over hbq (3.2MB/quarter, L2-resident).
// Masked lanes gather self -> d exactly 0.
// ---------------------------------------------------------------------------
__global__ __launch_bounds__(256) void gate4(
    const unsigned* __restrict__ hbq, const int* __restrict__ off_row,
    const int* __restrict__ by_row, float* __restrict__ out, int n, int nb_per_q)
{
    int qtr = blockIdx.x / nb_per_q;
    int blk = blockIdx.x - qtr * nb_per_q;
    int lane = threadIdx.x & 63;
    int wid = threadIdx.x >> 6;
    int fl = lane & 3, q16 = lane >> 2;

    const unsigned* tab = hbq + (size_t)qtr * ((size_t)n << 3);

    int node0 = (blk * 4 + wid) * NPW;
    for (int nn = 0; nn < NPW; ++nn) {
        int node = node0 + nn;
        if (node >= n) break;
        int s0 = off_row[node], s1 = off_row[node + 1];
        uint2 hp = ((const uint2*)tab)[((size_t)node << 2) + fl];
        v2f f01, f23;
        f01.x = __uint_as_float(hp.x << 16);
        f01.y = __uint_as_float(hp.x & 0xFFFF0000u);
        f23.x = __uint_as_float(hp.y << 16);
        f23.y = __uint_as_float(hp.y & 0xFFFF0000u);
        v2f a01 = {0.f, 0.f}, a23 = {0.f, 0.f};
        for (int base = s0; base < s1; base += 64) {
            int m = s1 - base;
            if (m > 64) m = 64;
            int idx = (lane < m) ? __builtin_nontemporal_load(by_row + base + lane) : node;
            for (int j = 0; j < m; j += 16) {
                int e = __shfl(idx, j + q16);
                uint2 v = ((const uint2*)tab)[((size_t)e << 2) + fl];
                v2f h01, h23;
                h01.x = __uint_as_float(v.x << 16);
                h01.y = __uint_as_float(v.x & 0xFFFF0000u);
                h23.x = __uint_as_float(v.y << 16);
                h23.y = __uint_as_float(v.y & 0xFFFF0000u);
                v2f d01 = f01 - h01;
                v2f d23 = f23 - h23;
                a01 += d01 * d01;
                a23 += d23 * d23;
            }
        }
        #pragma unroll
        for (int o = 4; o < 64; o <<= 1) {
            a01.x += __shfl_xor(a01.x, o);
            a01.y += __shfl_xor(a01.y, o);
            a23.x += __shfl_xor(a23.x, o);
            a23.y += __shfl_xor(a23.y, o);
        }
        if (lane < 4) {
            float inv = 1.f / fmaxf((float)(s1 - s0), 1.f);
            v4f o4;
            o4.x = fast_tanh_pos(a01.x * inv);
            o4.y = fast_tanh_pos(a01.y * inv);
            o4.z = fast_tanh_pos(a23.x * inv);
            o4.w = fast_tanh_pos(a23.y * inv);
            __builtin_nontemporal_store(
                o4, (v4f*)(out + ((size_t)node << 6) + qtr * 16) + fl);
        }
    }
}

extern "C" void kernel_launch(void* const* d_in, const int* in_sizes, int n_in,
                              void* d_out, int out_size, void* d_ws, size_t ws_size,
                              hipStream_t stream) {
    const float* X  = (const float*)d_in[0];
    const int*   ei = (const int*)d_in[1];
    const float* Wl = (const float*)d_in[2];
    const float* Wr = (const float*)d_in[3];
    const float* b  = (const float*)d_in[4];
    float* out = (float*)d_out;

    int n = in_sizes[0] / D;
    int n_edges = in_sizes[1] / 2;
    int nbk = (n + 127) >> 7;
    int nchunks = (n_edges + CHUNK - 1) / CHUNK;

    // ws layout (~72 MB); ylq has n+1 rows per quarter (row n = zeros)
    float* yrq = (float*)d_ws;                                 // n*64 f32 (quarter-major)
    unsigned* ylq = (unsigned*)(yrq + (size_t)n * D);          // 4*(n+1)*8 u32
    unsigned* hbq = ylq + ((size_t)(n + 1) << 5);              // n*32 u32 (quarter-major)
    unsigned short* wpack = (unsigned short*)(hbq + ((size_t)n << 5)); // 16384
    int* w = (int*)(wpack + 16384);
    int* bc_col    = w;                    // nbk
    int* bc_row    = bc_col + nbk;         // nbk
    int* bbase_col = bc_row + nbk;         // nbk
    int* bbase_row = bbase_col + nbk;      // nbk
    int* gcur_col  = bbase_row + nbk;      // nbk
    int* gcur_row  = gcur_col + nbk;       // nbk
    int* off_col   = gcur_row + nbk;       // n+1
    int* off_row   = off_col + (n + 1);    // n+1
    unsigned* ecol = (unsigned*)(off_row + (n + 1));   // n_edges
    unsigned* erow = ecol + n_edges;                   // n_edges
    int* by_col = (int*)(erow + n_edges);              // n_edges
    int* by_row = by_col + n_edges;                    // n_edges

    hipMemsetAsync(bc_col, 0, (size_t)2 * nbk * sizeof(int), stream);

    bucket_hist<<<nchunks + 1, MS_T, 0, stream>>>(ei, n_edges, nbk, bc_col, bc_row,
                                                  Wl, Wr, wpack, ylq, n);
    bucket_scan<<<1, 64, 0, stream>>>(bc_col, bc_row, bbase_col, bbase_row,
                                      gcur_col, gcur_row, nbk);
    multisplit<<<nchunks, MS_T, 0, stream>>>(ei, n_edges, nbk,
                                             gcur_col, gcur_row, ecol, erow);
    csr_build<<<2 * nbk, 256, 0, stream>>>(ecol, erow, bbase_col, bbase_row,
                                           bc_col, bc_row, off_col, off_row,
                                           by_col, by_row, n, nbk);

    int ngroups = (n + 15) / 16;
    gemm_x<<<(ngroups + 3) / 4, 256, 0, stream>>>(X, wpack, b, ylq, yrq, n, ngroups);

    // each block: 4 waves x NPW nodes = 16 nodes  (R3 bug: was /64 -> 3/4 of
    // nodes never processed)
    int nbq = (n + 4 * NPW - 1) / (4 * NPW);
    h_gather<<<4 * nbq, 256, 0, stream>>>(ylq, yrq, off_col, by_col, hbq, n, nbq);
    gate4<<<4 * nbq, 256, 0, stream>>>(hbq, off_row, by_row, out, n, nbq);
}

// Round 5
// 239.103 us; speedup vs baseline: 1.7072x; 1.7072x over previous
//
#include <hip/hip_runtime.h>
#include <math.h>

#define D 64
#define CHUNK 8192
#define MS_T 1024
#define EPT 8           // CHUNK / MS_T
#define MAXNB 800       // >= nbk = ceil(n/128); n=100000 -> 782

typedef __attribute__((ext_vector_type(8))) short frag_ab;
typedef __attribute__((ext_vector_type(4))) float frag_cd;
typedef __attribute__((ext_vector_type(2))) float v2f;

__device__ __forceinline__ unsigned short f2bf(float f) {
    unsigned u = __float_as_uint(f);
    u += 0x7FFFu + ((u >> 16) & 1u);
    return (unsigned short)(u >> 16);
}
__device__ __forceinline__ float bf2f(unsigned short s) {
    return __uint_as_float(((unsigned)s) << 16);
}
// tanh for x >= 0, branch-free, ~5 VALU. |err| ~1e-6 vs absmax budget 2e-2.
__device__ __forceinline__ float fast_tanh_pos(float x) {
    float t = __expf(-2.0f * x);
    return (1.0f - t) * __builtin_amdgcn_rcpf(1.0f + t);
}

// ---------------------------------------------------------------------------
// bucket_hist: per-chunk LDS histogram over 128-node buckets (verified).
// Last block instead packs W into MFMA fragment layout (verified) and zeroes
// yl row n (the masked-lane zero row).
// ---------------------------------------------------------------------------
__global__ __launch_bounds__(MS_T) void bucket_hist(
    const int* __restrict__ ei, int n_edges, int nbk,
    int* __restrict__ bc_col, int* __restrict__ bc_row,
    const float* __restrict__ Wl, const float* __restrict__ Wr,
    unsigned short* __restrict__ wpack, unsigned* __restrict__ yl, int n)
{
    __shared__ int scol[MAXNB];
    __shared__ int srow[MAXNB];

    if (blockIdx.x == gridDim.x - 1) {          // pack_w + zero row
        if (threadIdx.x < 256) {
            for (int c = threadIdx.x; c < 8192; c += 256) {
                int j = c & 7;
                int lane = (c >> 3) & 63;
                int tile = (c >> 9) & 7;
                int mat = c >> 12;
                int kc = tile >> 2;
                int nt = tile & 3;
                int krow = (lane >> 4) * 8 + j + kc * 32;
                int col = (lane & 15) + nt * 16;
                const float* W = mat ? Wr : Wl;
                float v = W[krow * 64 + col];
                unsigned short hi = f2bf(v);
                unsigned short lo = f2bf(v - bf2f(hi));
                int base = mat * 8192 + tile * 512 + lane * 8 + j;
                wpack[base] = hi;
                wpack[base + 4096] = lo;
            }
            if (threadIdx.x < 32)               // yl row n = zeros
                yl[((size_t)n << 5) + threadIdx.x] = 0u;
        }
        return;
    }

    for (int t = threadIdx.x; t < nbk; t += MS_T) {
        scol[t] = 0;
        srow[t] = 0;
    }
    __syncthreads();

    int base = blockIdx.x * CHUNK;
    int cc = n_edges - base;
    if (cc > CHUNK) cc = CHUNK;
    #pragma unroll
    for (int k = 0; k < EPT; ++k) {
        int i = threadIdx.x + k * MS_T;
        if (i < cc) {
            int r = ei[base + i];
            int c = ei[n_edges + base + i];
            atomicAdd(&srow[r >> 7], 1);
            atomicAdd(&scol[c >> 7], 1);
        }
    }
    __syncthreads();
    for (int t = threadIdx.x; t < nbk; t += MS_T) {
        if (scol[t]) atomicAdd(&bc_col[t], scol[t]);
        if (srow[t]) atomicAdd(&bc_row[t], srow[t]);
    }
}

// ---------------------------------------------------------------------------
// scan 782 bucket counts -> bases; init cursors (verified)
// ---------------------------------------------------------------------------
__global__ __launch_bounds__(64) void bucket_scan(
    const int* __restrict__ bc_col, const int* __restrict__ bc_row,
    int* __restrict__ bbase_col, int* __restrict__ bbase_row,
    int* __restrict__ gcur_col, int* __restrict__ gcur_row, int nbk)
{
    int lane = threadIdx.x;
    for (int w = 0; w < 2; ++w) {
        const int* bc = w ? bc_row : bc_col;
        int* bb = w ? bbase_row : bbase_col;
        int* gc = w ? gcur_row : gcur_col;
        int carry = 0;
        for (int b0 = 0; b0 < nbk; b0 += 64) {
            int v = (b0 + lane < nbk) ? bc[b0 + lane] : 0;
            int x = v;
            #pragma unroll
            for (int o = 1; o < 64; o <<= 1) {
                int u = __shfl_up(x, o);
                if (lane >= o) x += u;
            }
            if (b0 + lane < nbk) {
                int e = carry + x - v;
                bb[b0 + lane] = e;
                gc[b0 + lane] = e;
            }
            carry += __shfl(x, 63);
        }
    }
}

// ---------------------------------------------------------------------------
// Multisplit (verified): group edges into 128-node buckets, both orders.
// ---------------------------------------------------------------------------
__global__ __launch_bounds__(MS_T) void multisplit(
    const int* __restrict__ ei, int n_edges, int nbk,
    int* __restrict__ gcur_col, int* __restrict__ gcur_row,
    unsigned* __restrict__ ecol, unsigned* __restrict__ erow)
{
    __shared__ unsigned stage[CHUNK];
    __shared__ unsigned short sbk[CHUNK];
    __shared__ int cnt[MAXNB];
    __shared__ int off[MAXNB + 1];
    __shared__ int gb[MAXNB];

    int base = blockIdx.x * CHUNK;
    int cc = n_edges - base;
    if (cc > CHUNK) cc = CHUNK;

    int r[EPT], c[EPT];
    #pragma unroll
    for (int k = 0; k < EPT; ++k) {
        int i = threadIdx.x + k * MS_T;
        if (i < cc) {
            r[k] = ei[base + i];
            c[k] = ei[n_edges + base + i];
        }
    }

    for (int ord = 0; ord < 2; ++ord) {
        int* gcur = ord ? gcur_row : gcur_col;
        unsigned* eout = ord ? erow : ecol;

        for (int t = threadIdx.x; t < nbk; t += MS_T) cnt[t] = 0;
        __syncthreads();

        int rk[EPT], bk[EPT];
        #pragma unroll
        for (int k = 0; k < EPT; ++k) {
            int i = threadIdx.x + k * MS_T;
            if (i < cc) {
                int key = ord ? r[k] : c[k];
                bk[k] = key >> 7;
                rk[k] = atomicAdd(&cnt[bk[k]], 1);
            }
        }
        __syncthreads();

        if (threadIdx.x < 64) {           // wave 0: scan + global reservation
            int lane = threadIdx.x;
            int carry = 0;
            for (int b0 = 0; b0 < nbk; b0 += 64) {
                int v = (b0 + lane < nbk) ? cnt[b0 + lane] : 0;
                int x = v;
                #pragma unroll
                for (int o = 1; o < 64; o <<= 1) {
                    int u = __shfl_up(x, o);
                    if (lane >= o) x += u;
                }
                if (b0 + lane < nbk) {
                    off[b0 + lane] = carry + x - v;
                    gb[b0 + lane] = v ? atomicAdd(&gcur[b0 + lane], v) : 0;
                }
                carry += __shfl(x, 63);
            }
        }
        __syncthreads();

        #pragma unroll
        for (int k = 0; k < EPT; ++k) {
            int i = threadIdx.x + k * MS_T;
            if (i < cc) {
                int key = ord ? r[k] : c[k];
                int oth = ord ? c[k] : r[k];
                int p = off[bk[k]] + rk[k];
                stage[p] = ((unsigned)(key & 127) << 17) | (unsigned)oth;
                sbk[p] = (unsigned short)bk[k];
            }
        }
        __syncthreads();

        for (int t = threadIdx.x; t < cc; t += MS_T) {
            int bb = sbk[t];
            eout[gb[bb] + (t - off[bb])] = stage[t];
        }
        __syncthreads();
    }
}

// ---------------------------------------------------------------------------
// csr_build (verified): bucket entries -> exact per-node CSR.
// ---------------------------------------------------------------------------
__global__ __launch_bounds__(256) void csr_build(
    const unsigned* __restrict__ ecol, const unsigned* __restrict__ erow,
    const int* __restrict__ bbase_col, const int* __restrict__ bbase_row,
    const int* __restrict__ bc_col, const int* __restrict__ bc_row,
    int* __restrict__ off_col, int* __restrict__ off_row,
    int* __restrict__ by_col, int* __restrict__ by_row, int n, int nbk)
{
    __shared__ int scnt[128];
    __shared__ int soff[129];
    bool isRow = blockIdx.x >= (unsigned)nbk;
    int b = isRow ? (blockIdx.x - nbk) : blockIdx.x;
    const unsigned* e = isRow ? erow : ecol;
    int base = (isRow ? bbase_row : bbase_col)[b];
    int ec = (isRow ? bc_row : bc_col)[b];
    int* off_g = isRow ? off_row : off_col;
    int* by = isRow ? by_row : by_col;

    int node0 = b << 7;
    int nn = n - node0;
    if (nn > 128) nn = 128;

    if (threadIdx.x < 128) scnt[threadIdx.x] = 0;
    __syncthreads();

    for (int t = threadIdx.x; t < ec; t += 256)
        atomicAdd(&scnt[e[base + t] >> 17], 1);
    __syncthreads();

    if (threadIdx.x < 64) {
        int lane = threadIdx.x;
        int carry = 0;
        #pragma unroll
        for (int b0 = 0; b0 < 128; b0 += 64) {
            int v = scnt[b0 + lane];
            int x = v;
            #pragma unroll
            for (int o = 1; o < 64; o <<= 1) {
                int u = __shfl_up(x, o);
                if (lane >= o) x += u;
            }
            soff[b0 + lane] = carry + x - v;
            carry += __shfl(x, 63);
        }
        if (lane == 63) soff[128] = carry;
    }
    __syncthreads();

    if (threadIdx.x < 128) {
        if (threadIdx.x < nn) off_g[node0 + threadIdx.x] = base + soff[threadIdx.x];
        scnt[threadIdx.x] = 0;
    }
    if (threadIdx.x == 0 && node0 + nn == n) off_g[n] = base + soff[nn];
    __syncthreads();

    for (int t = threadIdx.x; t < ec; t += 256) {
        unsigned ent = e[base + t];
        int slot = ent >> 17;
        int r = atomicAdd(&scnt[slot], 1);
        by[base + soff[slot] + r] = (int)(ent & 0x1FFFF);
    }
}

// ---------------------------------------------------------------------------
// gemm_x: Yl = X@Wl (packed bf16 rows, xb-format) and Yr = X@Wr + b (f32
// rows), reading X once. mean(X[rows])@Wl == mean(Yl[rows]) by linearity.
// MFMA math identical to the verified linear_mfma (split-bf16, 3 MFMA/term).
// ---------------------------------------------------------------------------
__global__ __launch_bounds__(256) void gemm_x(
    const float* __restrict__ X, const unsigned short* __restrict__ wpack,
    const float* __restrict__ b, unsigned* __restrict__ yl,
    float* __restrict__ yr, int n, int ngroups)
{
    int lane = threadIdx.x & 63;
    int g = (blockIdx.x * blockDim.x + threadIdx.x) >> 6;
    if (g >= ngroups) return;
    int quad = lane >> 4;
    int l15 = lane & 15;

    frag_ab wf[2][2][2][4];
    #pragma unroll
    for (int mat = 0; mat < 2; ++mat)
        #pragma unroll
        for (int hf = 0; hf < 2; ++hf)
            #pragma unroll
            for (int kc = 0; kc < 2; ++kc)
                #pragma unroll
                for (int nt = 0; nt < 4; ++nt) {
                    const unsigned short* p =
                        wpack + mat * 8192 + hf * 4096 + (kc * 4 + nt) * 512 + lane * 8;
                    wf[mat][hf][kc][nt] = *(const frag_ab*)p;
                }

    frag_cd accl[4], accr[4];
    #pragma unroll
    for (int nt = 0; nt < 4; ++nt) {
        accl[nt] = (frag_cd){0.f, 0.f, 0.f, 0.f};
        accr[nt] = (frag_cd){0.f, 0.f, 0.f, 0.f};
    }

    int mrow = g * 16 + l15;
    if (mrow >= n) mrow = n - 1;
    const float* xrow = X + ((size_t)mrow << 6) + quad * 8;

    #pragma unroll
    for (int kc = 0; kc < 2; ++kc) {
        float xv[8];
        #pragma unroll
        for (int t = 0; t < 2; ++t) {
            float4 x4 = *(const float4*)(xrow + kc * 32 + t * 4);
            xv[t * 4 + 0] = x4.x; xv[t * 4 + 1] = x4.y;
            xv[t * 4 + 2] = x4.z; xv[t * 4 + 3] = x4.w;
        }
        frag_ab xh, xl;
        #pragma unroll
        for (int j = 0; j < 8; ++j) {
            unsigned short xbv = f2bf(xv[j]);
            xh[j] = (short)xbv;
            xl[j] = (short)f2bf(xv[j] - bf2f(xbv));
        }
        #pragma unroll
        for (int nt = 0; nt < 4; ++nt) {
            accl[nt] = __builtin_amdgcn_mfma_f32_16x16x32_bf16(xh, wf[0][0][kc][nt], accl[nt], 0, 0, 0);
            accl[nt] = __builtin_amdgcn_mfma_f32_16x16x32_bf16(xh, wf[0][1][kc][nt], accl[nt], 0, 0, 0);
            accl[nt] = __builtin_amdgcn_mfma_f32_16x16x32_bf16(xl, wf[0][0][kc][nt], accl[nt], 0, 0, 0);
            accr[nt] = __builtin_amdgcn_mfma_f32_16x16x32_bf16(xh, wf[1][0][kc][nt], accr[nt], 0, 0, 0);
            accr[nt] = __builtin_amdgcn_mfma_f32_16x16x32_bf16(xh, wf[1][1][kc][nt], accr[nt], 0, 0, 0);
            accr[nt] = __builtin_amdgcn_mfma_f32_16x16x32_bf16(xl, wf[1][0][kc][nt], accr[nt], 0, 0, 0);
        }
    }

    #pragma unroll
    for (int nt = 0; nt < 4; ++nt) {
        float bj = b[l15 + nt * 16];
        #pragma unroll
        for (int r = 0; r < 4; ++r) {
            int row = quad * 4 + r;
            int node = g * 16 + row;
            float vl = accl[nt][r];
            float vr = accr[nt][r] + bj;
            float vln = __shfl_xor(vl, 1);    // neighbor feature (l15^1)
            if (node < n) {
                yr[((size_t)node << 6) + nt * 16 + l15] = vr;
                if ((l15 & 1) == 0) {
                    unsigned pk = (unsigned)f2bf(vl) | ((unsigned)f2bf(vln) << 16);
                    yl[((size_t)node << 5) + nt * 8 + (l15 >> 1)] = pk;
                }
            }
        }
    }
}

// ---------------------------------------------------------------------------
// h_gather: baseline agg_gather structure (16 lanes/edge, uint2 loads,
// p-unroll 4, branch-free, packed-fp32 accumulate) gathering Yl rows; the
// epilogue finishes h = relu(mean + Yr) and writes packed-bf16 hb.
// ---------------------------------------------------------------------------
__global__ __launch_bounds__(256) void h_gather(
    const unsigned* __restrict__ yl, const float* __restrict__ yr,
    const int* __restrict__ off_col, const int* __restrict__ by_col,
    unsigned* __restrict__ hb, int n)
{
    int lane = threadIdx.x & 63;
    int node = (blockIdx.x * blockDim.x + threadIdx.x) >> 6;
    if (node >= n) return;
    int fl = lane & 15, q = lane >> 4;
    int s0 = off_col[node], s1 = off_col[node + 1];
    v2f a01 = {0.f, 0.f}, a23 = {0.f, 0.f};
    for (int base = s0; base < s1; base += 64) {
        int m = s1 - base;
        if (m > 64) m = 64;
        int idx = (lane < m) ? by_col[base + lane] : n;   // row n = zeros
        for (int j = 0; j < m; j += 16) {
            #pragma unroll
            for (int p = 0; p < 4; ++p) {
                int jj = j + 4 * p + q;                   // <= 63 always
                int e = __shfl(idx, jj);
                uint2 v = ((const uint2*)yl)[((size_t)e << 4) + fl];
                v2f h01, h23;
                h01.x = __uint_as_float(v.x << 16);
                h01.y = __uint_as_float(v.x & 0xFFFF0000u);
                h23.x = __uint_as_float(v.y << 16);
                h23.y = __uint_as_float(v.y & 0xFFFF0000u);
                a01 += h01;                               // v_pk_add_f32
                a23 += h23;
            }
        }
    }
    a01.x += __shfl_xor(a01.x, 16); a01.x += __shfl_xor(a01.x, 32);
    a01.y += __shfl_xor(a01.y, 16); a01.y += __shfl_xor(a01.y, 32);
    a23.x += __shfl_xor(a23.x, 16); a23.x += __shfl_xor(a23.x, 32);
    a23.y += __shfl_xor(a23.y, 16); a23.y += __shfl_xor(a23.y, 32);
    if (lane < 16) {
        float inv = 1.f / fmaxf((float)(s1 - s0), 1.f);
        float4 yv = ((const float4*)yr)[((size_t)node << 4) + fl];
        float h0 = fmaxf(a01.x * inv + yv.x, 0.f);
        float h1 = fmaxf(a01.y * inv + yv.y, 0.f);
        float h2 = fmaxf(a23.x * inv + yv.z, 0.f);
        float h3 = fmaxf(a23.y * inv + yv.w, 0.f);
        uint2 pk;
        pk.x = (unsigned)f2bf(h0) | ((unsigned)f2bf(h1) << 16);
        pk.y = (unsigned)f2bf(h2) | ((unsigned)f2bf(h3) << 16);
        ((uint2*)hb)[((size_t)node << 4) + fl] = pk;
    }
}

// ---------------------------------------------------------------------------
// Gate (byte-identical to the 246us baseline): 16 lanes/edge, uint2 loads,
// p-unroll 4, branch-free (masked -> self, d = 0 exactly), packed-fp32 math,
// fast tanh.
// ---------------------------------------------------------------------------
__global__ __launch_bounds__(256) void gate_kernel(
    const unsigned* __restrict__ hb, const int* __restrict__ off_row,
    const int* __restrict__ by_row, float* __restrict__ out, int n)
{
    int lane = threadIdx.x & 63;
    int u = (blockIdx.x * blockDim.x + threadIdx.x) >> 6;
    if (u >= n) return;
    int fl = lane & 15, q = lane >> 4;
    int s0 = off_row[u], s1 = off_row[u + 1];
    uint2 hp = ((const uint2*)hb)[((size_t)u << 4) + fl];
    v2f f01, f23;
    f01.x = __uint_as_float(hp.x << 16);
    f01.y = __uint_as_float(hp.x & 0xFFFF0000u);
    f23.x = __uint_as_float(hp.y << 16);
    f23.y = __uint_as_float(hp.y & 0xFFFF0000u);
    v2f a01 = {0.f, 0.f}, a23 = {0.f, 0.f};
    for (int base = s0; base < s1; base += 64) {
        int m = s1 - base;
        if (m > 64) m = 64;
        int idx = (lane < m) ? by_row[base + lane] : u;   // self -> d = 0
        for (int j = 0; j < m; j += 16) {
            #pragma unroll
            for (int p = 0; p < 4; ++p) {
                int jj = j + 4 * p + q;                   // <= 63 always
                int e = __shfl(idx, jj);
                uint2 v = ((const uint2*)hb)[((size_t)e << 4) + fl];
                v2f h01, h23;
                h01.x = __uint_as_float(v.x << 16);
                h01.y = __uint_as_float(v.x & 0xFFFF0000u);
                h23.x = __uint_as_float(v.y << 16);
                h23.y = __uint_as_float(v.y & 0xFFFF0000u);
                v2f d01 = f01 - h01;                      // v_pk_add (neg)
                v2f d23 = f23 - h23;
                a01 += d01 * d01;                         // v_pk_fma
                a23 += d23 * d23;
            }
        }
    }
    a01.x += __shfl_xor(a01.x, 16); a01.x += __shfl_xor(a01.x, 32);
    a01.y += __shfl_xor(a01.y, 16); a01.y += __shfl_xor(a01.y, 32);
    a23.x += __shfl_xor(a23.x, 16); a23.x += __shfl_xor(a23.x, 32);
    a23.y += __shfl_xor(a23.y, 16); a23.y += __shfl_xor(a23.y, 32);
    if (lane < 16) {
        float inv = 1.f / fmaxf((float)(s1 - s0), 1.f);
        float4 o;
        o.x = fast_tanh_pos(a01.x * inv);
        o.y = fast_tanh_pos(a01.y * inv);
        o.z = fast_tanh_pos(a23.x * inv);
        o.w = fast_tanh_pos(a23.y * inv);
        ((float4*)out)[((size_t)u << 4) + fl] = o;
    }
}

extern "C" void kernel_launch(void* const* d_in, const int* in_sizes, int n_in,
                              void* d_out, int out_size, void* d_ws, size_t ws_size,
                              hipStream_t stream) {
    const float* X  = (const float*)d_in[0];
    const int*   ei = (const int*)d_in[1];
    const float* Wl = (const float*)d_in[2];
    const float* Wr = (const float*)d_in[3];
    const float* b  = (const float*)d_in[4];
    float* out = (float*)d_out;

    int n = in_sizes[0] / D;
    int n_edges = in_sizes[1] / 2;
    int nbk = (n + 127) >> 7;
    int nchunks = (n_edges + CHUNK - 1) / CHUNK;

    // ws layout (~72 MB); yl has n+1 rows (row n = zeros)
    float* yr = (float*)d_ws;                                  // n*64 f32
    unsigned* yl = (unsigned*)(yr + (size_t)n * D);            // (n+1)*32 u32
    unsigned* hb = yl + (size_t)(n + 1) * 32;                  // n*32 u32
    unsigned short* wpack = (unsigned short*)(hb + (size_t)n * 32); // 16384
    int* w = (int*)(wpack + 16384);
    int* bc_col    = w;                    // nbk
    int* bc_row    = bc_col + nbk;         // nbk
    int* bbase_col = bc_row + nbk;         // nbk
    int* bbase_row = bbase_col + nbk;      // nbk
    int* gcur_col  = bbase_row + nbk;      // nbk
    int* gcur_row  = gcur_col + nbk;       // nbk
    int* off_col   = gcur_row + nbk;       // n+1
    int* off_row   = off_col + (n + 1);    // n+1
    unsigned* ecol = (unsigned*)(off_row + (n + 1));   // n_edges
    unsigned* erow = ecol + n_edges;                   // n_edges
    int* by_col = (int*)(erow + n_edges);              // n_edges
    int* by_row = by_col + n_edges;                    // n_edges

    hipMemsetAsync(bc_col, 0, (size_t)2 * nbk * sizeof(int), stream);

    bucket_hist<<<nchunks + 1, MS_T, 0, stream>>>(ei, n_edges, nbk, bc_col, bc_row,
                                                  Wl, Wr, wpack, yl, n);
    bucket_scan<<<1, 64, 0, stream>>>(bc_col, bc_row, bbase_col, bbase_row,
                                      gcur_col, gcur_row, nbk);
    multisplit<<<nchunks, MS_T, 0, stream>>>(ei, n_edges, nbk,
                                             gcur_col, gcur_row, ecol, erow);
    csr_build<<<2 * nbk, 256, 0, stream>>>(ecol, erow, bbase_col, bbase_row,
                                           bc_col, bc_row, off_col, off_row,
                                           by_col, by_row, n, nbk);

    int ngroups = (n + 15) / 16;
    gemm_x<<<(ngroups + 3) / 4, 256, 0, stream>>>(X, wpack, b, yl, yr, n, ngroups);

    h_gather<<<(n + 3) / 4, 256, 0, stream>>>(yl, yr, off_col, by_col, hb, n);
    gate_kernel<<<(n + 3) / 4, 256, 0, stream>>>(hb, off_row, by_row, out, n);
}